// Round 3
// baseline (221.107 us; speedup 1.0000x reference)
//
#include <hip/hip_runtime.h>

#define LOG2E 1.4426950408889634f
#define LN2   0.6931471805599453f

#if __has_builtin(__builtin_amdgcn_exp2f)
#define EXP2(x) __builtin_amdgcn_exp2f(x)
#else
#define EXP2(x) exp2f(x)
#endif
#if __has_builtin(__builtin_amdgcn_logf)
#define LOG2(x) __builtin_amdgcn_logf(x)
#else
#define LOG2(x) log2f(x)
#endif

constexpr int BB = 4096;
constexpr int S  = 512;
constexpr int NT = 9;
constexpr int TD = 11;
constexpr int CH = 64;        // scan steps per LDS chunk
constexpr int CF = CH * NT;   // 576 floats per chunk

__device__ __forceinline__ float rdlane(float v, int l) {
    return __uint_as_float(__builtin_amdgcn_readlane(__float_as_uint(v), l));
}

// One block = 256 threads = 4 waves; ONE batch row per wave.
// Phase A: real path score + length (64 lanes strided over t).
// Phase B: 9-state forward scan in log2 domain; lane j owns alpha[j].
//   - cross-lane broadcast via v_readlane (SGPR), not ds_bpermute
//   - proxy max m = alpha[0] refreshed every step (readlane), so e0 == 1
//   - emissions double-buffered in LDS: 9 coalesced global loads per
//     64-step chunk, issued one chunk ahead; scan does 1 ds_read_b32/step
__global__ __launch_bounds__(256) void crf_fused(
    const float* __restrict__ em,    // [B][S][9]
    const int*   __restrict__ mask,  // [B][S]
    const int*   __restrict__ tags,  // [B][S]
    const float* __restrict__ trans, // [11][11]
    float* __restrict__ blkV,        // [grid] partial sum(total - real)
    float* __restrict__ blkN)        // [grid] partial num_chars
{
    __shared__ float sm[4][2][CF];
    __shared__ float s_val[4];
    __shared__ float s_n[4];

    const int tid = threadIdx.x;
    const int wv_id = tid >> 6;   // wave within block
    const int l     = tid & 63;   // lane
    const int b     = blockIdx.x * 4 + wv_id;

    const float* emB   = em + (size_t)b * (S * NT);
    const int*   maskB = mask + b * S;
    const int*   tagsB = tags + b * S;

    // issue chunk-0 emission loads early (consumed by ds_write after Phase A)
    float pf[9];
    #pragma unroll
    for (int r = 0; r < 9; ++r) pf[r] = emB[r * 64 + l];

    // ---------------- Phase A: real score + length ----------------
    float sumE = 0.f;
    int   cnt  = 0;
    int   prevcarry = 0;

    #pragma unroll 2
    for (int i = 0; i < S / 64; ++i) {
        int   t  = i * 64 + l;
        int   mk = maskB[t];
        int   tg = tagsB[t];
        float gv = emB[t * NT + tg];
        int   tgp = __shfl_up(tg, 1);
        if (l == 0) tgp = prevcarry;
        float tr = (t > 0) ? trans[tgp * TD + tg] : 0.f;
        prevcarry = __shfl(tg, 63);
        if (mk) { sumE += gv + tr; cnt++; }
    }
    #pragma unroll
    for (int d = 1; d < 64; d <<= 1) {
        sumE += __shfl_xor(sumE, d);
        cnt  += __shfl_xor(cnt, d);
    }
    const int L = cnt;                       // this row's length (prefix mask)

    if (l == 0) {
        int tg0 = tagsB[0];
        int tgl = tagsB[L - 1];
        sumE += trans[9 * TD + tg0] + trans[tgl * TD + 10];
    }

    // ---------------- Phase B: forward scan ----------------
    const bool active = (l < NT);
    const int  jj = active ? l : 0;

    float w[NT];                              // w[i] = 2^(T[i][jj]*log2e)
    #pragma unroll
    for (int i = 0; i < NT; ++i)
        w[i] = EXP2(trans[i * TD + jj] * LOG2E);

    float a = (trans[9 * TD + jj] + emB[jj]) * LOG2E;   // alpha0 (log2 units)
    if (!active) a = -1e30f;
    float m = rdlane(a, 0);                   // proxy max = alpha[0]
    float e = active ? EXP2(a - m) : 0.f;     // e0 == 1 by construction

    // stage chunk 0 into LDS buffer 0
    #pragma unroll
    for (int r = 0; r < 9; ++r) sm[wv_id][0][r * 64 + l] = pf[r];

    for (int c = 0; c * CH < L; ++c) {
        int cn = c + 1;
        if (cn > S / CH - 1) cn = S / CH - 1; // clamp (stay inside this row)
        #pragma unroll
        for (int r = 0; r < 9; ++r)           // async prefetch next chunk
            pf[r] = emB[cn * CF + r * 64 + l];

        const float* buf = sm[wv_id][c & 1];
        const int base = c * CH;
        int t0 = base < 1 ? 1 : base;
        int t1 = base + CH; if (t1 > L) t1 = L;

        #pragma unroll 4
        for (int tt = t0; tt < t1; ++tt) {
            float emv = buf[(tt - base) * NT + jj];   // scan-independent addr

            float e1 = rdlane(e, 1);
            float e2 = rdlane(e, 2);
            float e3 = rdlane(e, 3);
            float e4 = rdlane(e, 4);
            float e5 = rdlane(e, 5);
            float e6 = rdlane(e, 6);
            float e7 = rdlane(e, 7);
            float e8 = rdlane(e, 8);

            float d0 = fmaf(e1, w[1], w[0]);          // e0 == 1
            d0 = fmaf(e2, w[2], d0);
            float d1 = e3 * w[3];
            d1 = fmaf(e4, w[4], d1);
            d1 = fmaf(e5, w[5], d1);
            float d2 = e6 * w[6];
            d2 = fmaf(e7, w[7], d2);
            d2 = fmaf(e8, w[8], d2);
            float dot = (d0 + d1) + d2;

            float anew = fmaf(emv, LOG2E, m) + LOG2(dot);
            a = active ? anew : a;
            m = rdlane(a, 0);                 // fresh proxy max, uniform
            e = EXP2(a - m);                  // inactive: 2^(-huge) -> 0
        }

        #pragma unroll
        for (int r = 0; r < 9; ++r)           // stage prefetched chunk
            sm[wv_id][cn & 1][r * 64 + l] = pf[r];
    }

    // total = ln( sum_j exp(alpha_j + T[j,end]) )
    float v  = active ? (a + trans[jj * TD + 10] * LOG2E) : -1e30f;
    float m2 = v;
    #pragma unroll
    for (int d = 1; d < 16; d <<= 1) m2 = fmaxf(m2, __shfl_xor(m2, d, 16));
    float sv = active ? EXP2(v - m2) : 0.f;
    #pragma unroll
    for (int d = 1; d < 16; d <<= 1) sv += __shfl_xor(sv, d, 16);

    if (l == 0) {
        float total = (m2 + LOG2(sv)) * LN2;
        s_val[wv_id] = total - sumE;
        s_n[wv_id]   = (float)L;
    }
    __syncthreads();
    if (tid == 0) {
        blkV[blockIdx.x] = s_val[0] + s_val[1] + s_val[2] + s_val[3];
        blkN[blockIdx.x] = s_n[0] + s_n[1] + s_n[2] + s_n[3];
    }
}

// Reduce 1024 per-block partials and divide.
__global__ __launch_bounds__(256) void crf_final(
    const float* __restrict__ blkV,
    const float* __restrict__ blkN,
    float* __restrict__ out)
{
    const int tid = threadIdx.x;
    float v = 0.f, n = 0.f;
    #pragma unroll
    for (int i = 0; i < 4; ++i) {
        v += blkV[tid + i * 256];
        n += blkN[tid + i * 256];
    }
    #pragma unroll
    for (int d = 1; d < 64; d <<= 1) {
        v += __shfl_xor(v, d);
        n += __shfl_xor(n, d);
    }
    __shared__ float sv[4], sn[4];
    if ((tid & 63) == 0) { sv[tid >> 6] = v; sn[tid >> 6] = n; }
    __syncthreads();
    if (tid == 0) {
        out[0] = (sv[0] + sv[1] + sv[2] + sv[3]) /
                 (sn[0] + sn[1] + sn[2] + sn[3]);
    }
}

extern "C" void kernel_launch(void* const* d_in, const int* in_sizes, int n_in,
                              void* d_out, int out_size, void* d_ws, size_t ws_size,
                              hipStream_t stream) {
    const float* em    = (const float*)d_in[0];
    const int*   mask  = (const int*)d_in[1];
    const int*   tags  = (const int*)d_in[2];
    const float* trans = (const float*)d_in[3];
    float* blkV = (float*)d_ws;            // 1024 floats
    float* blkN = blkV + 1024;             // 1024 floats

    crf_fused<<<BB / 4, 256, 0, stream>>>(em, mask, tags, trans, blkV, blkN);
    crf_final<<<1, 256, 0, stream>>>(blkV, blkN, (float*)d_out);
}